// Round 1
// baseline (1946.315 us; speedup 1.0000x reference)
//
#include <hip/hip_runtime.h>

#define NN 100000
#define NE 1600000
#define DF 128
#define ROWS 8

// ---------------------------------------------------------------------------
// deg[n] = number of edges with dst == n  (float, exact for counts < 2^24)
// ---------------------------------------------------------------------------
__global__ void deg_kernel(const int* __restrict__ dst, float* __restrict__ deg) {
    int e = blockIdx.x * blockDim.x + threadIdx.x;
    if (e < NE) atomicAdd(&deg[dst[e]], 1.0f);
}

// ---------------------------------------------------------------------------
// sums[dst[e], d] += feat[src[e], d]   one thread per (edge, feature)
// consecutive threads cover consecutive d -> coalesced 512B gather per edge
// ---------------------------------------------------------------------------
__global__ void scatter_kernel(const float* __restrict__ feat,
                               const int* __restrict__ src,
                               const int* __restrict__ dst,
                               float* __restrict__ sums) {
    unsigned idx = blockIdx.x * blockDim.x + threadIdx.x;
    if (idx >= (unsigned)NE * DF) return;
    unsigned e = idx >> 7;          // edge id
    unsigned d = idx & 127u;        // feature id
    int s = src[e];
    int t = dst[e];
    atomicAdd(&sums[(unsigned)t * DF + d], feat[(unsigned)s * DF + d]);
}

// ---------------------------------------------------------------------------
// out[n, j] = act( (sums[n,:] / max(deg[n],1)) @ Wl[:,j] + b[j] + selfF[n,:] @ Wr[:,j] )
// Block: 128 threads (thread = output col j), ROWS nodes per block.
// A-rows staged in LDS (broadcast reads, conflict-free); W rows read
// coalesced from L2 and reused ROWS times per block.
// ---------------------------------------------------------------------------
template <bool RELU>
__global__ __launch_bounds__(128) void gemm_fused(
        const float* __restrict__ sums, const float* __restrict__ deg,
        const float* __restrict__ selfF,
        const float* __restrict__ Wl, const float* __restrict__ bias,
        const float* __restrict__ Wr, float* __restrict__ out) {
    __shared__ float sAgg[ROWS][DF];
    __shared__ float sX[ROWS][DF];

    const int j  = threadIdx.x;          // 0..127
    const int n0 = blockIdx.x * ROWS;

    #pragma unroll
    for (int r = 0; r < ROWS; ++r) {
        int n = n0 + r;
        float scale = 1.0f / fmaxf(deg[n], 1.0f);
        sAgg[r][j] = sums[(size_t)n * DF + j] * scale;
        sX[r][j]   = selfF[(size_t)n * DF + j];
    }
    __syncthreads();

    float acc[ROWS];
    const float bj = bias[j];
    #pragma unroll
    for (int r = 0; r < ROWS; ++r) acc[r] = bj;

    for (int k = 0; k < DF; ++k) {
        float wl = Wl[k * DF + j];
        float wr = Wr[k * DF + j];
        #pragma unroll
        for (int r = 0; r < ROWS; ++r)
            acc[r] += sAgg[r][k] * wl + sX[r][k] * wr;
    }

    #pragma unroll
    for (int r = 0; r < ROWS; ++r) {
        float v = acc[r];
        if (RELU) v = fmaxf(v, 0.0f);
        out[(size_t)(n0 + r) * DF + j] = v;
    }
}

// ---------------------------------------------------------------------------
extern "C" void kernel_launch(void* const* d_in, const int* in_sizes, int n_in,
                              void* d_out, int out_size, void* d_ws, size_t ws_size,
                              hipStream_t stream) {
    const float* x   = (const float*)d_in[0];
    const int*   ei  = (const int*)d_in[1];   // [2, NE] int32
    const float* W1l = (const float*)d_in[2];
    const float* b1  = (const float*)d_in[3];
    const float* W1r = (const float*)d_in[4];
    const float* W2l = (const float*)d_in[5];
    const float* b2  = (const float*)d_in[6];
    const float* W2r = (const float*)d_in[7];
    float*       out = (float*)d_out;

    const int* src = ei;
    const int* dst = ei + NE;

    char* ws = (char*)d_ws;
    const size_t feat_bytes = (size_t)NN * DF * sizeof(float);   // 51.2 MB
    float* sums = (float*)ws;
    float* deg  = (float*)(ws + feat_bytes);
    float* h    = (float*)(ws + feat_bytes + (size_t)NN * sizeof(float));

    // zero sums + deg (contiguous)
    hipMemsetAsync(sums, 0, feat_bytes + (size_t)NN * sizeof(float), stream);

    deg_kernel<<<(NE + 255) / 256, 256, 0, stream>>>(dst, deg);

    const unsigned scatter_elems = (unsigned)NE * DF;            // 204.8M
    const unsigned scatter_blocks = (scatter_elems + 255) / 256; // 800000

    // ---- layer 1 ----
    scatter_kernel<<<scatter_blocks, 256, 0, stream>>>(x, src, dst, sums);
    gemm_fused<true><<<NN / ROWS, 128, 0, stream>>>(sums, deg, x, W1l, b1, W1r, h);

    // ---- layer 2 ----
    hipMemsetAsync(sums, 0, feat_bytes, stream);
    scatter_kernel<<<scatter_blocks, 256, 0, stream>>>(h, src, dst, sums);
    gemm_fused<false><<<NN / ROWS, 128, 0, stream>>>(sums, deg, h, W2l, b2, W2r, out);
}

// Round 2
// 895.913 us; speedup vs baseline: 2.1724x; 2.1724x over previous
//
#include <hip/hip_runtime.h>

#define NN 100000
#define NE 1600000
#define DF 128
#define ROWS 8

// ---------------------------------------------------------------------------
// In-degree histogram: deg_i[dst[e]]++
// ---------------------------------------------------------------------------
__global__ void hist_kernel(const int* __restrict__ dst, int* __restrict__ deg_i) {
    int e = blockIdx.x * blockDim.x + threadIdx.x;
    if (e < NE) atomicAdd(&deg_i[dst[e]], 1);
}

// ---------------------------------------------------------------------------
// Segment assignment: ofs[n] = running total of deg_i (order arbitrary).
// Block-level scan + ONE atomic per block on the global counter.
// ---------------------------------------------------------------------------
__global__ __launch_bounds__(256) void ofs_kernel(const int* __restrict__ deg_i,
                                                  int* __restrict__ ctr,
                                                  int* __restrict__ ofs) {
    __shared__ int sd[256];
    __shared__ int base;
    int n = blockIdx.x * 256 + threadIdx.x;
    int v = (n < NN) ? deg_i[n] : 0;
    sd[threadIdx.x] = v;
    __syncthreads();
    // Hillis-Steele inclusive scan
    for (int off = 1; off < 256; off <<= 1) {
        int t = (threadIdx.x >= off) ? sd[threadIdx.x - off] : 0;
        __syncthreads();
        sd[threadIdx.x] += t;
        __syncthreads();
    }
    if (threadIdx.x == 255) base = atomicAdd(ctr, sd[255]);
    __syncthreads();
    if (n < NN) ofs[n] = base + sd[threadIdx.x] - v;  // exclusive within block
}

// ---------------------------------------------------------------------------
// CSR fill: ssrc[ofs[dst] + slot] = src
// ---------------------------------------------------------------------------
__global__ void fill_kernel(const int* __restrict__ src, const int* __restrict__ dst,
                            const int* __restrict__ ofs, int* __restrict__ cur,
                            int* __restrict__ ssrc) {
    int e = blockIdx.x * blockDim.x + threadIdx.x;
    if (e < NE) {
        int t = dst[e];
        int p = atomicAdd(&cur[t], 1);
        ssrc[ofs[t] + p] = src[e];
    }
}

// ---------------------------------------------------------------------------
// Gather aggregation: one WAVE per node, lane reads float2 (64*8B = 512B row).
// agg[n,:] = mean over in-edges of feat[src,:]
// ---------------------------------------------------------------------------
__global__ __launch_bounds__(256) void agg_kernel(const float* __restrict__ feat,
                                                  const int* __restrict__ ssrc,
                                                  const int* __restrict__ ofs,
                                                  const int* __restrict__ deg_i,
                                                  float* __restrict__ agg) {
    int w = threadIdx.x >> 6;       // wave id in block (0..3)
    int lane = threadIdx.x & 63;
    int n = blockIdx.x * 4 + w;     // NN % 4 == 0
    int start = ofs[n];
    int len = deg_i[n];
    const float2* base = (const float2*)feat;
    float ax = 0.0f, ay = 0.0f;
    for (int i = 0; i < len; ++i) {
        int s = ssrc[start + i];
        float2 v = base[(size_t)s * 64 + lane];
        ax += v.x;
        ay += v.y;
    }
    float inv = 1.0f / fmaxf((float)len, 1.0f);
    float2 r;
    r.x = ax * inv;
    r.y = ay * inv;
    ((float2*)agg)[(size_t)n * 64 + lane] = r;
}

// ---------------------------------------------------------------------------
// out[n, j] = act( agg[n,:] @ Wl[:,j] + b[j] + selfF[n,:] @ Wr[:,j] )
// 128 threads (thread = col j), ROWS nodes per block, float4 LDS reads.
// Safe for selfF == out (in-place): block reads its own rows into LDS
// (with __syncthreads) before writing them.
// ---------------------------------------------------------------------------
template <bool RELU>
__global__ __launch_bounds__(128) void gemm_fused(
        const float* __restrict__ agg, const float* __restrict__ selfF,
        const float* __restrict__ Wl, const float* __restrict__ bias,
        const float* __restrict__ Wr, float* __restrict__ out) {
    __shared__ float sAgg[ROWS][DF];
    __shared__ float sX[ROWS][DF];

    const int j  = threadIdx.x;          // 0..127
    const int n0 = blockIdx.x * ROWS;

    #pragma unroll
    for (int r = 0; r < ROWS; ++r) {
        int n = n0 + r;
        sAgg[r][j] = agg[(size_t)n * DF + j];
        sX[r][j]   = selfF[(size_t)n * DF + j];
    }
    __syncthreads();

    float acc[ROWS];
    const float bj = bias[j];
    #pragma unroll
    for (int r = 0; r < ROWS; ++r) acc[r] = bj;

    for (int k = 0; k < DF; k += 4) {
        float wl[4], wr[4];
        #pragma unroll
        for (int i = 0; i < 4; ++i) {
            wl[i] = Wl[(k + i) * DF + j];
            wr[i] = Wr[(k + i) * DF + j];
        }
        #pragma unroll
        for (int r = 0; r < ROWS; ++r) {
            float4 a  = *(const float4*)&sAgg[r][k];
            float4 xx = *(const float4*)&sX[r][k];
            acc[r] += a.x * wl[0] + a.y * wl[1] + a.z * wl[2] + a.w * wl[3]
                    + xx.x * wr[0] + xx.y * wr[1] + xx.z * wr[2] + xx.w * wr[3];
        }
    }

    #pragma unroll
    for (int r = 0; r < ROWS; ++r) {
        float v = acc[r];
        if (RELU) v = fmaxf(v, 0.0f);
        out[(size_t)(n0 + r) * DF + j] = v;
    }
}

// ---------------------------------------------------------------------------
extern "C" void kernel_launch(void* const* d_in, const int* in_sizes, int n_in,
                              void* d_out, int out_size, void* d_ws, size_t ws_size,
                              hipStream_t stream) {
    const float* x   = (const float*)d_in[0];
    const int*   ei  = (const int*)d_in[1];   // [2, NE] int32
    const float* W1l = (const float*)d_in[2];
    const float* b1  = (const float*)d_in[3];
    const float* W1r = (const float*)d_in[4];
    const float* W2l = (const float*)d_in[5];
    const float* b2  = (const float*)d_in[6];
    const float* W2r = (const float*)d_in[7];
    float*       out = (float*)d_out;

    const int* src = ei;
    const int* dst = ei + NE;

    // workspace layout
    char* ws = (char*)d_ws;
    int*   deg_i = (int*)(ws);                         // NN ints
    int*   cur   = (int*)(ws + 400000);                // NN ints
    int*   ctr   = (int*)(ws + 800000);                // 1 int (+pad)
    int*   ofs   = (int*)(ws + 800128);                // NN ints
    int*   ssrc  = (int*)(ws + 1200128);               // NE ints
    float* agg   = (float*)(ws + 7600128);             // NN*DF floats (16B aligned)
    float* h     = out;                                // layer-1 hidden lives in d_out

    // zero deg_i, cur, ctr in one shot
    hipMemsetAsync(ws, 0, 800132, stream);

    // ---- CSR build (shared by both layers) ----
    hist_kernel<<<(NE + 255) / 256, 256, 0, stream>>>(dst, deg_i);
    ofs_kernel<<<(NN + 255) / 256, 256, 0, stream>>>(deg_i, ctr, ofs);
    fill_kernel<<<(NE + 255) / 256, 256, 0, stream>>>(src, dst, ofs, cur, ssrc);

    // ---- layer 1 ----
    agg_kernel<<<NN / 4, 256, 0, stream>>>(x, ssrc, ofs, deg_i, agg);
    gemm_fused<true><<<NN / ROWS, 128, 0, stream>>>(agg, x, W1l, b1, W1r, h);

    // ---- layer 2 (in-place on d_out) ----
    agg_kernel<<<NN / 4, 256, 0, stream>>>(h, ssrc, ofs, deg_i, agg);
    gemm_fused<false><<<NN / ROWS, 128, 0, stream>>>(agg, h, W2l, b2, W2r, out);
}

// Round 3
// 559.768 us; speedup vs baseline: 3.4770x; 1.6005x over previous
//
#include <hip/hip_runtime.h>

#define NN 100000
#define NE 1600000
#define DF 128

typedef short short8 __attribute__((ext_vector_type(8)));
typedef float floatx4 __attribute__((ext_vector_type(4)));
typedef unsigned int uint;
typedef unsigned short ushort;

// float -> bf16 (RNE, no NaN handling needed: all values finite)
static __device__ __forceinline__ ushort f2bf(float f) {
    uint u = __builtin_bit_cast(uint, f);
    return (ushort)((u + 0x7fffu + ((u >> 16) & 1u)) >> 16);
}
static __device__ __forceinline__ float bf2f_lo(uint v) {   // low 16 bits
    return __builtin_bit_cast(float, v << 16);
}
static __device__ __forceinline__ float bf2f_hi(uint v) {   // high 16 bits
    return __builtin_bit_cast(float, v & 0xffff0000u);
}

// ---------------------------------------------------------------------------
// In-degree histogram
// ---------------------------------------------------------------------------
__global__ void hist_kernel(const int* __restrict__ dst, int* __restrict__ deg_i) {
    int e = blockIdx.x * blockDim.x + threadIdx.x;
    if (e < NE) atomicAdd(&deg_i[dst[e]], 1);
}

// ---------------------------------------------------------------------------
// Segment offsets: block scan + one atomic per block (order arbitrary)
// ---------------------------------------------------------------------------
__global__ __launch_bounds__(256) void ofs_kernel(const int* __restrict__ deg_i,
                                                  int* __restrict__ ctr,
                                                  int* __restrict__ ofs) {
    __shared__ int sd[256];
    __shared__ int base;
    int n = blockIdx.x * 256 + threadIdx.x;
    int v = (n < NN) ? deg_i[n] : 0;
    sd[threadIdx.x] = v;
    __syncthreads();
    for (int off = 1; off < 256; off <<= 1) {
        int t = (threadIdx.x >= off) ? sd[threadIdx.x - off] : 0;
        __syncthreads();
        sd[threadIdx.x] += t;
        __syncthreads();
    }
    if (threadIdx.x == 255) base = atomicAdd(ctr, sd[255]);
    __syncthreads();
    if (n < NN) ofs[n] = base + sd[threadIdx.x] - v;
}

// ---------------------------------------------------------------------------
// CSR fill
// ---------------------------------------------------------------------------
__global__ void fill_kernel(const int* __restrict__ src, const int* __restrict__ dst,
                            const int* __restrict__ ofs, int* __restrict__ cur,
                            int* __restrict__ ssrc) {
    int e = blockIdx.x * blockDim.x + threadIdx.x;
    if (e < NE) {
        int t = dst[e];
        int p = atomicAdd(&cur[t], 1);
        ssrc[ofs[t] + p] = src[e];
    }
}

// ---------------------------------------------------------------------------
// x (fp32) -> xb (bf16), 4 elements per thread
// ---------------------------------------------------------------------------
__global__ void conv_x_kernel(const float* __restrict__ x, ushort* __restrict__ xb) {
    int i = blockIdx.x * 256 + threadIdx.x;      // < NN*DF/4
    if (i < NN * DF / 4) {
        float4 v = ((const float4*)x)[i];
        uint lo = (uint)f2bf(v.x) | ((uint)f2bf(v.y) << 16);
        uint hi = (uint)f2bf(v.z) | ((uint)f2bf(v.w) << 16);
        ((uint2*)xb)[i] = make_uint2(lo, hi);
    }
}

// ---------------------------------------------------------------------------
// W^T build: WT[n][k] (n<128 cols, k<256) = bf16( k<128 ? Wl[k][n] : Wr[k-128][n] )
// one thread per (n,k) element, both layers
// ---------------------------------------------------------------------------
__global__ void conv_w_kernel(const float* __restrict__ W1l, const float* __restrict__ W1r,
                              const float* __restrict__ W2l, const float* __restrict__ W2r,
                              ushort* __restrict__ WT1, ushort* __restrict__ WT2) {
    int id = blockIdx.x * 256 + threadIdx.x;     // < 32768; id = n*256 + k
    if (id < 128 * 256) {
        int n = id >> 8, k = id & 255;
        float a = (k < 128) ? W1l[k * 128 + n] : W1r[(k - 128) * 128 + n];
        float b = (k < 128) ? W2l[k * 128 + n] : W2r[(k - 128) * 128 + n];
        WT1[id] = f2bf(a);
        WT2[id] = f2bf(b);
    }
}

// ---------------------------------------------------------------------------
// Mean aggregation over bf16 rows: one wave per node, lane reads 4B (2 feats),
// fp32 accumulation, bf16 output. 4x unrolled for memory-level parallelism.
// ---------------------------------------------------------------------------
__global__ __launch_bounds__(256) void agg_bf16(const ushort* __restrict__ feat,
                                                const int* __restrict__ ssrc,
                                                const int* __restrict__ ofs,
                                                const int* __restrict__ deg_i,
                                                ushort* __restrict__ aggb) {
    int w = threadIdx.x >> 6;
    int lane = threadIdx.x & 63;
    int n = blockIdx.x * 4 + w;                  // NN % 4 == 0
    int start = ofs[n];
    int len = deg_i[n];
    const uint* src = (const uint*)feat;
    float ax = 0.0f, ay = 0.0f;
    int i = 0;
    for (; i + 4 <= len; i += 4) {
        int s0 = ssrc[start + i];
        int s1 = ssrc[start + i + 1];
        int s2 = ssrc[start + i + 2];
        int s3 = ssrc[start + i + 3];
        uint v0 = src[(size_t)s0 * 64 + lane];
        uint v1 = src[(size_t)s1 * 64 + lane];
        uint v2 = src[(size_t)s2 * 64 + lane];
        uint v3 = src[(size_t)s3 * 64 + lane];
        ax += bf2f_lo(v0) + bf2f_lo(v1) + bf2f_lo(v2) + bf2f_lo(v3);
        ay += bf2f_hi(v0) + bf2f_hi(v1) + bf2f_hi(v2) + bf2f_hi(v3);
    }
    for (; i < len; ++i) {
        uint v = src[(size_t)ssrc[start + i] * 64 + lane];
        ax += bf2f_lo(v);
        ay += bf2f_hi(v);
    }
    float inv = 1.0f / fmaxf((float)len, 1.0f);
    ((uint*)aggb)[(size_t)n * 64 + lane] =
        (uint)f2bf(ax * inv) | ((uint)f2bf(ay * inv) << 16);
}

// ---------------------------------------------------------------------------
// Fused GEMM: C[n,j] = act( [agg|self][n,:] @ WT[j,:] + bias[j] )
// K=256. Block = 256 threads (4 waves), 64 nodes/block, each wave does a
// 16-node x 128-col stripe as 8 MFMA 16x16x32 tiles. A staged in LDS
// (row stride 264 ushorts = 528B: 16B-aligned b128, 2-way bank alias only).
// B fragments straight from global WT (64KB, L2-hot).
// ---------------------------------------------------------------------------
template <int RELU, int BF16OUT>
__global__ __launch_bounds__(256) void gemm_mfma(
        const ushort* __restrict__ aggb, const ushort* __restrict__ selfb,
        const ushort* __restrict__ WT, const float* __restrict__ bias,
        void* __restrict__ outv) {
    __shared__ ushort sA[64][264];
    const int tid = threadIdx.x;
    const int blk = blockIdx.x;

    // ---- stage A = [agg | self] (64 rows x 256 bf16) ----
    #pragma unroll
    for (int it = 0; it < 8; ++it) {
        int flat = tid + it * 256;               // 0..2047
        int row = flat >> 5;                     // 32 x 16B chunks per row
        int chunk = flat & 31;
        int node = blk * 64 + row;
        int cn = node < NN ? node : NN - 1;
        const ushort* sp = (chunk < 16)
            ? (aggb + (size_t)cn * 128 + chunk * 8)
            : (selfb + (size_t)cn * 128 + (chunk - 16) * 8);
        uint4 v = *(const uint4*)sp;
        *(uint4*)&sA[row][chunk * 8] = v;
    }
    __syncthreads();

    const int w = tid >> 6;
    const int lane = tid & 63;
    const int m = lane & 15;                     // A row / B col / C col index
    const int q = lane >> 4;                     // quad

    floatx4 acc[8];
    #pragma unroll
    for (int t = 0; t < 8; ++t) acc[t] = (floatx4){0.f, 0.f, 0.f, 0.f};

    #pragma unroll
    for (int kk = 0; kk < 8; ++kk) {             // K = 8 * 32
        short8 a = *(const short8*)&sA[w * 16 + m][kk * 32 + q * 8];
        #pragma unroll
        for (int t = 0; t < 8; ++t) {
            short8 b = *(const short8*)(WT + (size_t)(t * 16 + m) * 256 + kk * 32 + q * 8);
            acc[t] = __builtin_amdgcn_mfma_f32_16x16x32_bf16(a, b, acc[t], 0, 0, 0);
        }
    }

    // ---- epilogue: C/D layout col=lane&15, row=q*4+reg ----
    const int node_base = blk * 64 + w * 16 + q * 4;
    #pragma unroll
    for (int t = 0; t < 8; ++t) {
        int col = t * 16 + m;
        float bj = bias[col];
        #pragma unroll
        for (int r = 0; r < 4; ++r) {
            int node = node_base + r;
            if (node < NN) {
                float v = acc[t][r] + bj;
                if (RELU) v = fmaxf(v, 0.0f);
                if (BF16OUT)
                    ((ushort*)outv)[(size_t)node * 128 + col] = f2bf(v);
                else
                    ((float*)outv)[(size_t)node * 128 + col] = v;
            }
        }
    }
}

// ---------------------------------------------------------------------------
extern "C" void kernel_launch(void* const* d_in, const int* in_sizes, int n_in,
                              void* d_out, int out_size, void* d_ws, size_t ws_size,
                              hipStream_t stream) {
    const float* x   = (const float*)d_in[0];
    const int*   ei  = (const int*)d_in[1];
    const float* W1l = (const float*)d_in[2];
    const float* b1  = (const float*)d_in[3];
    const float* W1r = (const float*)d_in[4];
    const float* W2l = (const float*)d_in[5];
    const float* b2  = (const float*)d_in[6];
    const float* W2r = (const float*)d_in[7];
    float*       out = (float*)d_out;

    const int* src = ei;
    const int* dst = ei + NE;

    // workspace layout (bytes)
    char* ws = (char*)d_ws;
    int*    deg_i = (int*)(ws);                  // 400000
    int*    cur   = (int*)(ws + 400000);         // 400000
    int*    ctr   = (int*)(ws + 800000);         // 128
    int*    ofs   = (int*)(ws + 800128);         // 400000
    int*    ssrc  = (int*)(ws + 1200128);        // 6400000
    ushort* WT1   = (ushort*)(ws + 7600128);     // 65536
    ushort* WT2   = (ushort*)(ws + 7665664);     // 65536
    ushort* xb    = (ushort*)(ws + 7731200);     // 25600000
    ushort* aggb  = (ushort*)(ws + 33331200);    // 25600000
    ushort* hb    = (ushort*)(ws + 58931200);    // 25600000  (end 84.5MB)

    hipMemsetAsync(ws, 0, 800128, stream);       // deg_i, cur, ctr

    // ---- CSR build (shared by both layers) ----
    hist_kernel<<<(NE + 255) / 256, 256, 0, stream>>>(dst, deg_i);
    ofs_kernel<<<(NN + 255) / 256, 256, 0, stream>>>(deg_i, ctr, ofs);
    fill_kernel<<<(NE + 255) / 256, 256, 0, stream>>>(src, dst, ofs, cur, ssrc);

    // ---- conversions ----
    conv_x_kernel<<<(NN * DF / 4 + 255) / 256, 256, 0, stream>>>(x, xb);
    conv_w_kernel<<<128, 256, 0, stream>>>(W1l, W1r, W2l, W2r, WT1, WT2);

    const int gemm_grid = (NN + 63) / 64;

    // ---- layer 1 ----
    agg_bf16<<<NN / 4, 256, 0, stream>>>(xb, ssrc, ofs, deg_i, aggb);
    gemm_mfma<1, 1><<<gemm_grid, 256, 0, stream>>>(aggb, xb, WT1, b1, hb);

    // ---- layer 2 ----
    agg_bf16<<<NN / 4, 256, 0, stream>>>(hb, ssrc, ofs, deg_i, aggb);
    gemm_mfma<0, 0><<<gemm_grid, 256, 0, stream>>>(aggb, hb, WT2, b2, out);
}

// Round 4
// 479.045 us; speedup vs baseline: 4.0629x; 1.1685x over previous
//
#include <hip/hip_runtime.h>

#define NN 100000
#define NE 1600000
#define DF 128

typedef short short8 __attribute__((ext_vector_type(8)));
typedef float floatx4 __attribute__((ext_vector_type(4)));
typedef unsigned int uint;
typedef unsigned short ushort;

// float -> bf16 (RNE; inputs finite)
static __device__ __forceinline__ ushort f2bf(float f) {
    uint u = __builtin_bit_cast(uint, f);
    return (ushort)((u + 0x7fffu + ((u >> 16) & 1u)) >> 16);
}
static __device__ __forceinline__ float bf2f_lo(uint v) {
    return __builtin_bit_cast(float, v << 16);
}
static __device__ __forceinline__ float bf2f_hi(uint v) {
    return __builtin_bit_cast(float, v & 0xffff0000u);
}

// ---------------------------------------------------------------------------
// In-degree histogram
// ---------------------------------------------------------------------------
__global__ void hist_kernel(const int* __restrict__ dst, int* __restrict__ deg_i) {
    int e = blockIdx.x * blockDim.x + threadIdx.x;
    if (e < NE) atomicAdd(&deg_i[dst[e]], 1);
}

// ---------------------------------------------------------------------------
// Segment offsets: block scan + one atomic per block (order arbitrary)
// ---------------------------------------------------------------------------
__global__ __launch_bounds__(256) void ofs_kernel(const int* __restrict__ deg_i,
                                                  int* __restrict__ ctr,
                                                  int* __restrict__ ofs) {
    __shared__ int sd[256];
    __shared__ int base;
    int n = blockIdx.x * 256 + threadIdx.x;
    int v = (n < NN) ? deg_i[n] : 0;
    sd[threadIdx.x] = v;
    __syncthreads();
    for (int off = 1; off < 256; off <<= 1) {
        int t = (threadIdx.x >= off) ? sd[threadIdx.x - off] : 0;
        __syncthreads();
        sd[threadIdx.x] += t;
        __syncthreads();
    }
    if (threadIdx.x == 255) base = atomicAdd(ctr, sd[255]);
    __syncthreads();
    if (n < NN) ofs[n] = base + sd[threadIdx.x] - v;
}

// ---------------------------------------------------------------------------
// CSR fill: atomicAdd directly on ofs (returns slot); afterwards ofs[n] = end.
// ---------------------------------------------------------------------------
__global__ void fill_kernel(const int* __restrict__ src, const int* __restrict__ dst,
                            int* __restrict__ ofs, int* __restrict__ ssrc) {
    int e = blockIdx.x * blockDim.x + threadIdx.x;
    if (e < NE) {
        int p = atomicAdd(&ofs[dst[e]], 1);
        ssrc[p] = src[e];
    }
}

// ---------------------------------------------------------------------------
// x (fp32) -> xb (bf16)
// ---------------------------------------------------------------------------
__global__ void conv_x_kernel(const float* __restrict__ x, ushort* __restrict__ xb) {
    int i = blockIdx.x * 256 + threadIdx.x;
    if (i < NN * DF / 4) {
        float4 v = ((const float4*)x)[i];
        uint lo = (uint)f2bf(v.x) | ((uint)f2bf(v.y) << 16);
        uint hi = (uint)f2bf(v.z) | ((uint)f2bf(v.w) << 16);
        ((uint2*)xb)[i] = make_uint2(lo, hi);
    }
}

// ---------------------------------------------------------------------------
// W^T build: WT[n][k] (n<128, k<256) = bf16( k<128 ? Wl[k][n] : Wr[k-128][n] )
// ---------------------------------------------------------------------------
__global__ void conv_w_kernel(const float* __restrict__ W1l, const float* __restrict__ W1r,
                              const float* __restrict__ W2l, const float* __restrict__ W2r,
                              ushort* __restrict__ WT1, ushort* __restrict__ WT2) {
    int id = blockIdx.x * 256 + threadIdx.x;
    if (id < 128 * 256) {
        int n = id >> 8, k = id & 255;
        float a = (k < 128) ? W1l[k * 128 + n] : W1r[(k - 128) * 128 + n];
        float b = (k < 128) ? W2l[k * 128 + n] : W2r[(k - 128) * 128 + n];
        WT1[id] = f2bf(a);
        WT2[id] = f2bf(b);
    }
}

// ---------------------------------------------------------------------------
// Mean aggregation: 16 lanes per node, each lane reads uint4 (8 bf16, 16B) —
// 16 lanes x 16B = one 256B row per gather. 4x unrolled. start = ofs[n]-len.
// ---------------------------------------------------------------------------
__global__ __launch_bounds__(256) void agg_bf16(const ushort* __restrict__ feat,
                                                const int* __restrict__ ssrc,
                                                const int* __restrict__ ofs,
                                                const int* __restrict__ deg_i,
                                                ushort* __restrict__ aggb) {
    int g = threadIdx.x >> 4;       // node slot 0..15
    int l = threadIdx.x & 15;       // 16B chunk within row
    int n = blockIdx.x * 16 + g;    // NN % 16 == 0
    int len = deg_i[n];
    int start = ofs[n] - len;       // ofs holds segment END after fill
    const uint4* fb = (const uint4*)feat;   // row stride = 16 uint4
    float ac[8] = {0.f, 0.f, 0.f, 0.f, 0.f, 0.f, 0.f, 0.f};
    int i = 0;
    for (; i + 4 <= len; i += 4) {
        int s0 = ssrc[start + i];
        int s1 = ssrc[start + i + 1];
        int s2 = ssrc[start + i + 2];
        int s3 = ssrc[start + i + 3];
        uint4 v0 = fb[(size_t)s0 * 16 + l];
        uint4 v1 = fb[(size_t)s1 * 16 + l];
        uint4 v2 = fb[(size_t)s2 * 16 + l];
        uint4 v3 = fb[(size_t)s3 * 16 + l];
        ac[0] += bf2f_lo(v0.x) + bf2f_lo(v1.x) + bf2f_lo(v2.x) + bf2f_lo(v3.x);
        ac[1] += bf2f_hi(v0.x) + bf2f_hi(v1.x) + bf2f_hi(v2.x) + bf2f_hi(v3.x);
        ac[2] += bf2f_lo(v0.y) + bf2f_lo(v1.y) + bf2f_lo(v2.y) + bf2f_lo(v3.y);
        ac[3] += bf2f_hi(v0.y) + bf2f_hi(v1.y) + bf2f_hi(v2.y) + bf2f_hi(v3.y);
        ac[4] += bf2f_lo(v0.z) + bf2f_lo(v1.z) + bf2f_lo(v2.z) + bf2f_lo(v3.z);
        ac[5] += bf2f_hi(v0.z) + bf2f_hi(v1.z) + bf2f_hi(v2.z) + bf2f_hi(v3.z);
        ac[6] += bf2f_lo(v0.w) + bf2f_lo(v1.w) + bf2f_lo(v2.w) + bf2f_lo(v3.w);
        ac[7] += bf2f_hi(v0.w) + bf2f_hi(v1.w) + bf2f_hi(v2.w) + bf2f_hi(v3.w);
    }
    for (; i < len; ++i) {
        uint4 v = fb[(size_t)ssrc[start + i] * 16 + l];
        ac[0] += bf2f_lo(v.x); ac[1] += bf2f_hi(v.x);
        ac[2] += bf2f_lo(v.y); ac[3] += bf2f_hi(v.y);
        ac[4] += bf2f_lo(v.z); ac[5] += bf2f_hi(v.z);
        ac[6] += bf2f_lo(v.w); ac[7] += bf2f_hi(v.w);
    }
    float inv = 1.0f / fmaxf((float)len, 1.0f);
    uint4 r;
    r.x = (uint)f2bf(ac[0] * inv) | ((uint)f2bf(ac[1] * inv) << 16);
    r.y = (uint)f2bf(ac[2] * inv) | ((uint)f2bf(ac[3] * inv) << 16);
    r.z = (uint)f2bf(ac[4] * inv) | ((uint)f2bf(ac[5] * inv) << 16);
    r.w = (uint)f2bf(ac[6] * inv) | ((uint)f2bf(ac[7] * inv) << 16);
    ((uint4*)aggb)[(size_t)n * 16 + l] = r;
}

// ---------------------------------------------------------------------------
// Fused GEMM: C[n,j] = act( [agg|self][n,:] @ WT[j,:] + bias[j] ), K=256.
// 512 threads = 8 waves, 16 rows/wave -> 128 rows/block. WT staged in LDS
// (XOR chunk swizzle, exactly 64KB -> 2 blocks/CU). A-fragments read straight
// from global (16 lanes x 16B = 16 full cache lines, coalesced, all 8 loads
// independent -> deep prefetch).
// ---------------------------------------------------------------------------
template <int RELU, int BF16OUT>
__global__ __launch_bounds__(512, 4) void gemm_mfma(
        const ushort* __restrict__ aggb, const ushort* __restrict__ selfb,
        const ushort* __restrict__ WT, const float* __restrict__ bias,
        void* __restrict__ outv) {
    __shared__ ushort sWT[128 * 256];            // 64KB, swizzled chunks
    const int tid = threadIdx.x;
    const int blk = blockIdx.x;

    // ---- stage WT: chunk c (8 ushorts) of col stored at c ^ (col&7) ----
    #pragma unroll
    for (int it = 0; it < 8; ++it) {
        int flat = it * 512 + tid;               // 0..4095
        int col = flat >> 5;
        int c = flat & 31;
        uint4 v = *(const uint4*)(WT + (size_t)col * 256 + c * 8);
        *(uint4*)&sWT[col * 256 + (c ^ (col & 7)) * 8] = v;
    }

    const int w = tid >> 6;
    const int lane = tid & 63;
    const int m = lane & 15;
    const int q = lane >> 4;

    // ---- A fragments straight from global ----
    int node_m = blk * 128 + w * 16 + m;
    int cn = node_m < NN ? node_m : NN - 1;
    const ushort* arow = aggb + (size_t)cn * 128;
    const ushort* xrow = selfb + (size_t)cn * 128;
    short8 a[8];
    #pragma unroll
    for (int kk = 0; kk < 4; ++kk) {
        a[kk]     = *(const short8*)(arow + kk * 32 + q * 8);
        a[4 + kk] = *(const short8*)(xrow + kk * 32 + q * 8);
    }

    __syncthreads();

    floatx4 acc[8];
    #pragma unroll
    for (int t = 0; t < 8; ++t) acc[t] = (floatx4){0.f, 0.f, 0.f, 0.f};

    const int m7 = m & 7;
    #pragma unroll
    for (int kk = 0; kk < 8; ++kk) {
        int cx = (kk * 4 + q) ^ m7;              // swizzled chunk index
        #pragma unroll
        for (int t = 0; t < 8; ++t) {
            short8 b = *(const short8*)&sWT[(t * 16 + m) * 256 + cx * 8];
            acc[t] = __builtin_amdgcn_mfma_f32_16x16x32_bf16(a[kk], b, acc[t], 0, 0, 0);
        }
    }

    // ---- epilogue: C/D layout col=lane&15, row=q*4+reg ----
    const int node_base = blk * 128 + w * 16 + q * 4;
    #pragma unroll
    for (int t = 0; t < 8; ++t) {
        int col = t * 16 + m;
        float bj = bias[col];
        #pragma unroll
        for (int r = 0; r < 4; ++r) {
            int node = node_base + r;
            if (node < NN) {
                float v = acc[t][r] + bj;
                if (RELU) v = fmaxf(v, 0.0f);
                if (BF16OUT)
                    ((ushort*)outv)[(size_t)node * 128 + col] = f2bf(v);
                else
                    ((float*)outv)[(size_t)node * 128 + col] = v;
            }
        }
    }
}

// ---------------------------------------------------------------------------
extern "C" void kernel_launch(void* const* d_in, const int* in_sizes, int n_in,
                              void* d_out, int out_size, void* d_ws, size_t ws_size,
                              hipStream_t stream) {
    const float* x   = (const float*)d_in[0];
    const int*   ei  = (const int*)d_in[1];
    const float* W1l = (const float*)d_in[2];
    const float* b1  = (const float*)d_in[3];
    const float* W1r = (const float*)d_in[4];
    const float* W2l = (const float*)d_in[5];
    const float* b2  = (const float*)d_in[6];
    const float* W2r = (const float*)d_in[7];
    float*       out = (float*)d_out;

    const int* src = ei;
    const int* dst = ei + NE;

    // workspace layout (bytes)
    char* ws = (char*)d_ws;
    int*    deg_i = (int*)(ws);                  // 400000
    int*    ctr   = (int*)(ws + 400000);         // 128
    int*    ofs   = (int*)(ws + 400128);         // 400000
    int*    ssrc  = (int*)(ws + 800128);         // 6400000
    ushort* WT1   = (ushort*)(ws + 7200128);     // 65536
    ushort* WT2   = (ushort*)(ws + 7265664);     // 65536
    ushort* xb    = (ushort*)(ws + 7331200);     // 25600000
    ushort* aggb  = (ushort*)(ws + 32931200);    // 25600000
    ushort* hb    = (ushort*)(ws + 58531200);    // 25600000 (end 84.1MB)

    hipMemsetAsync(ws, 0, 400128, stream);       // deg_i + ctr

    // ---- CSR build (shared by both layers) ----
    hist_kernel<<<(NE + 255) / 256, 256, 0, stream>>>(dst, deg_i);
    ofs_kernel<<<(NN + 255) / 256, 256, 0, stream>>>(deg_i, ctr, ofs);
    fill_kernel<<<(NE + 255) / 256, 256, 0, stream>>>(src, dst, ofs, ssrc);

    // ---- conversions ----
    conv_x_kernel<<<(NN * DF / 4 + 255) / 256, 256, 0, stream>>>(x, xb);
    conv_w_kernel<<<128, 256, 0, stream>>>(W1l, W1r, W2l, W2r, WT1, WT2);

    const int gemm_grid = (NN + 127) / 128;

    // ---- layer 1 ----
    agg_bf16<<<NN / 16, 256, 0, stream>>>(xb, ssrc, ofs, deg_i, aggb);
    gemm_mfma<1, 1><<<gemm_grid, 512, 0, stream>>>(aggb, xb, WT1, b1, hb);

    // ---- layer 2 ----
    agg_bf16<<<NN / 16, 256, 0, stream>>>(hb, ssrc, ofs, deg_i, aggb);
    gemm_mfma<0, 0><<<gemm_grid, 512, 0, stream>>>(aggb, hb, WT2, b2, out);
}

// Round 5
// 448.575 us; speedup vs baseline: 4.3389x; 1.0679x over previous
//
#include <hip/hip_runtime.h>

#define NN 100000
#define NE 1600000
#define DF 128

typedef short short8 __attribute__((ext_vector_type(8)));
typedef float floatx4 __attribute__((ext_vector_type(4)));
typedef unsigned int uint;
typedef unsigned short ushort;

// float -> bf16 (RNE; inputs finite)
static __device__ __forceinline__ ushort f2bf(float f) {
    uint u = __builtin_bit_cast(uint, f);
    return (ushort)((u + 0x7fffu + ((u >> 16) & 1u)) >> 16);
}
static __device__ __forceinline__ float bf2f_lo(uint v) {
    return __builtin_bit_cast(float, v << 16);
}
static __device__ __forceinline__ float bf2f_hi(uint v) {
    return __builtin_bit_cast(float, v & 0xffff0000u);
}

// ---------------------------------------------------------------------------
// Linked-list build: two chains per node (even/odd edge) for chase MLP.
// nxt[e] write is perfectly coalesced; head (800KB) churns in L2.
// ---------------------------------------------------------------------------
__global__ void build_ll(const int* __restrict__ dst,
                         int* __restrict__ head, int* __restrict__ nxt) {
    int e = blockIdx.x * blockDim.x + threadIdx.x;
    if (e < NE) {
        int h = dst[e] * 2 + (e & 1);
        nxt[e] = atomicExch(&head[h], e);
    }
}

// ---------------------------------------------------------------------------
// x (fp32) -> xb (bf16)
// ---------------------------------------------------------------------------
__global__ void conv_x_kernel(const float* __restrict__ x, ushort* __restrict__ xb) {
    int i = blockIdx.x * 256 + threadIdx.x;
    if (i < NN * DF / 4) {
        float4 v = ((const float4*)x)[i];
        uint lo = (uint)f2bf(v.x) | ((uint)f2bf(v.y) << 16);
        uint hi = (uint)f2bf(v.z) | ((uint)f2bf(v.w) << 16);
        ((uint2*)xb)[i] = make_uint2(lo, hi);
    }
}

// ---------------------------------------------------------------------------
// W^T build: WT[n][k] (n<128, k<256) = bf16( k<128 ? Wl[k][n] : Wr[k-128][n] )
// ---------------------------------------------------------------------------
__global__ void conv_w_kernel(const float* __restrict__ W1l, const float* __restrict__ W1r,
                              const float* __restrict__ W2l, const float* __restrict__ W2r,
                              ushort* __restrict__ WT1, ushort* __restrict__ WT2) {
    int id = blockIdx.x * 256 + threadIdx.x;
    if (id < 128 * 256) {
        int n = id >> 8, k = id & 255;
        float a = (k < 128) ? W1l[k * 128 + n] : W1r[(k - 128) * 128 + n];
        float b = (k < 128) ? W2l[k * 128 + n] : W2r[(k - 128) * 128 + n];
        WT1[id] = f2bf(a);
        WT2[id] = f2bf(b);
    }
}

// ---------------------------------------------------------------------------
// Mean aggregation via linked-list chase: 16 lanes per node (lane reads 16B),
// two chains per node chased concurrently (2x MLP on the nxt recurrence).
// Counts degree on the fly — no deg array.
// ---------------------------------------------------------------------------
static __device__ __forceinline__ void acc8(float* ac, uint4 v) {
    ac[0] += bf2f_lo(v.x); ac[1] += bf2f_hi(v.x);
    ac[2] += bf2f_lo(v.y); ac[3] += bf2f_hi(v.y);
    ac[4] += bf2f_lo(v.z); ac[5] += bf2f_hi(v.z);
    ac[6] += bf2f_lo(v.w); ac[7] += bf2f_hi(v.w);
}

__global__ __launch_bounds__(256) void agg_ll(const ushort* __restrict__ feat,
                                              const int* __restrict__ src,
                                              const int* __restrict__ head,
                                              const int* __restrict__ nxt,
                                              ushort* __restrict__ aggb) {
    int g = threadIdx.x >> 4;       // node slot 0..15
    int l = threadIdx.x & 15;       // 16B chunk within row
    int n = blockIdx.x * 16 + g;    // NN % 16 == 0
    const uint4* fb = (const uint4*)feat;   // row stride = 16 uint4

    int c0 = head[n * 2];
    int c1 = head[n * 2 + 1];
    float ac[8] = {0.f, 0.f, 0.f, 0.f, 0.f, 0.f, 0.f, 0.f};
    int cnt = 0;

    while (c0 >= 0 && c1 >= 0) {
        int n0 = nxt[c0], n1 = nxt[c1];          // recurrence loads first
        int s0 = src[c0], s1 = src[c1];
        uint4 v0 = fb[(size_t)s0 * 16 + l];
        uint4 v1 = fb[(size_t)s1 * 16 + l];
        acc8(ac, v0);
        acc8(ac, v1);
        cnt += 2;
        c0 = n0; c1 = n1;
    }
    while (c0 >= 0) {
        int n0 = nxt[c0];
        uint4 v = fb[(size_t)src[c0] * 16 + l];
        acc8(ac, v);
        cnt++;
        c0 = n0;
    }
    while (c1 >= 0) {
        int n1 = nxt[c1];
        uint4 v = fb[(size_t)src[c1] * 16 + l];
        acc8(ac, v);
        cnt++;
        c1 = n1;
    }

    float inv = 1.0f / fmaxf((float)cnt, 1.0f);
    uint4 r;
    r.x = (uint)f2bf(ac[0] * inv) | ((uint)f2bf(ac[1] * inv) << 16);
    r.y = (uint)f2bf(ac[2] * inv) | ((uint)f2bf(ac[3] * inv) << 16);
    r.z = (uint)f2bf(ac[4] * inv) | ((uint)f2bf(ac[5] * inv) << 16);
    r.w = (uint)f2bf(ac[6] * inv) | ((uint)f2bf(ac[7] * inv) << 16);
    ((uint4*)aggb)[(size_t)n * 16 + l] = r;
}

// ---------------------------------------------------------------------------
// Fused GEMM: C[n,j] = act( [agg|self][n,:] @ WT[j,:] + bias[j] ), K=256.
// 512 threads = 8 waves, 16 rows/wave -> 128 rows/block. WT staged in LDS
// (XOR chunk swizzle, exactly 64KB). A-fragments straight from global
// (16 lanes x 16B = 16 full cache lines, all 8 loads independent).
// ---------------------------------------------------------------------------
template <int RELU, int BF16OUT>
__global__ __launch_bounds__(512, 4) void gemm_mfma(
        const ushort* __restrict__ aggb, const ushort* __restrict__ selfb,
        const ushort* __restrict__ WT, const float* __restrict__ bias,
        void* __restrict__ outv) {
    __shared__ ushort sWT[128 * 256];            // 64KB, swizzled chunks
    const int tid = threadIdx.x;
    const int blk = blockIdx.x;

    // ---- stage WT: chunk c (8 ushorts) of col stored at c ^ (col&7) ----
    #pragma unroll
    for (int it = 0; it < 8; ++it) {
        int flat = it * 512 + tid;               // 0..4095
        int col = flat >> 5;
        int c = flat & 31;
        uint4 v = *(const uint4*)(WT + (size_t)col * 256 + c * 8);
        *(uint4*)&sWT[col * 256 + (c ^ (col & 7)) * 8] = v;
    }

    const int w = tid >> 6;
    const int lane = tid & 63;
    const int m = lane & 15;
    const int q = lane >> 4;

    // ---- A fragments straight from global ----
    int node_m = blk * 128 + w * 16 + m;
    int cn = node_m < NN ? node_m : NN - 1;
    const ushort* arow = aggb + (size_t)cn * 128;
    const ushort* xrow = selfb + (size_t)cn * 128;
    short8 a[8];
    #pragma unroll
    for (int kk = 0; kk < 4; ++kk) {
        a[kk]     = *(const short8*)(arow + kk * 32 + q * 8);
        a[4 + kk] = *(const short8*)(xrow + kk * 32 + q * 8);
    }

    __syncthreads();

    floatx4 acc[8];
    #pragma unroll
    for (int t = 0; t < 8; ++t) acc[t] = (floatx4){0.f, 0.f, 0.f, 0.f};

    const int m7 = m & 7;
    #pragma unroll
    for (int kk = 0; kk < 8; ++kk) {
        int cx = (kk * 4 + q) ^ m7;              // swizzled chunk index
        #pragma unroll
        for (int t = 0; t < 8; ++t) {
            short8 b = *(const short8*)&sWT[(t * 16 + m) * 256 + cx * 8];
            acc[t] = __builtin_amdgcn_mfma_f32_16x16x32_bf16(a[kk], b, acc[t], 0, 0, 0);
        }
    }

    // ---- epilogue: C/D layout col=lane&15, row=q*4+reg ----
    const int node_base = blk * 128 + w * 16 + q * 4;
    #pragma unroll
    for (int t = 0; t < 8; ++t) {
        int col = t * 16 + m;
        float bj = bias[col];
        #pragma unroll
        for (int r = 0; r < 4; ++r) {
            int node = node_base + r;
            if (node < NN) {
                float v = acc[t][r] + bj;
                if (RELU) v = fmaxf(v, 0.0f);
                if (BF16OUT)
                    ((ushort*)outv)[(size_t)node * 128 + col] = f2bf(v);
                else
                    ((float*)outv)[(size_t)node * 128 + col] = v;
            }
        }
    }
}

// ---------------------------------------------------------------------------
extern "C" void kernel_launch(void* const* d_in, const int* in_sizes, int n_in,
                              void* d_out, int out_size, void* d_ws, size_t ws_size,
                              hipStream_t stream) {
    const float* x   = (const float*)d_in[0];
    const int*   ei  = (const int*)d_in[1];
    const float* W1l = (const float*)d_in[2];
    const float* b1  = (const float*)d_in[3];
    const float* W1r = (const float*)d_in[4];
    const float* W2l = (const float*)d_in[5];
    const float* b2  = (const float*)d_in[6];
    const float* W2r = (const float*)d_in[7];
    float*       out = (float*)d_out;

    const int* src = ei;
    const int* dst = ei + NE;

    // workspace layout (bytes)
    char* ws = (char*)d_ws;
    int*    head = (int*)(ws);                   // 800000 (2 per node)
    int*    nxt  = (int*)(ws + 800000);          // 6400000
    ushort* WT1  = (ushort*)(ws + 7200000);      // 65536
    ushort* WT2  = (ushort*)(ws + 7265536);      // 65536
    ushort* xb   = (ushort*)(ws + 7331072);      // 25600000
    ushort* aggb = (ushort*)(ws + 32931072);     // 25600000
    ushort* hb   = (ushort*)(ws + 58531072);     // 25600000 (end 84.1MB)

    hipMemsetAsync(head, 0xFF, 800000, stream);  // heads = -1

    build_ll<<<(NE + 255) / 256, 256, 0, stream>>>(dst, head, nxt);
    conv_x_kernel<<<(NN * DF / 4 + 255) / 256, 256, 0, stream>>>(x, xb);
    conv_w_kernel<<<128, 256, 0, stream>>>(W1l, W1r, W2l, W2r, WT1, WT2);

    const int gemm_grid = (NN + 127) / 128;

    // ---- layer 1 ----
    agg_ll<<<NN / 16, 256, 0, stream>>>(xb, src, head, nxt, aggb);
    gemm_mfma<1, 1><<<gemm_grid, 512, 0, stream>>>(aggb, xb, WT1, b1, hb);

    // ---- layer 2 ----
    agg_ll<<<NN / 16, 256, 0, stream>>>(hb, src, head, nxt, aggb);
    gemm_mfma<0, 0><<<gemm_grid, 512, 0, stream>>>(aggb, hb, WT2, b2, out);
}

// Round 6
// 403.005 us; speedup vs baseline: 4.8295x; 1.1131x over previous
//
#include <hip/hip_runtime.h>

#define NN 100000
#define NE 1600000
#define DF 128

typedef short short8 __attribute__((ext_vector_type(8)));
typedef float floatx4 __attribute__((ext_vector_type(4)));
typedef float floatx2 __attribute__((ext_vector_type(2)));
typedef unsigned int uint;
typedef unsigned short ushort;

// float -> bf16 (RNE; inputs finite)
static __device__ __forceinline__ ushort f2bf(float f) {
    uint u = __builtin_bit_cast(uint, f);
    return (ushort)((u + 0x7fffu + ((u >> 16) & 1u)) >> 16);
}
static __device__ __forceinline__ float bf2f_lo(uint v) {
    return __builtin_bit_cast(float, v << 16);
}
static __device__ __forceinline__ float bf2f_hi(uint v) {
    return __builtin_bit_cast(float, v & 0xffff0000u);
}

// ---------------------------------------------------------------------------
// Linked-list build: two chains per node (even/odd edge) for chase MLP.
// ---------------------------------------------------------------------------
__global__ void build_ll(const int* __restrict__ dst,
                         int* __restrict__ head, int* __restrict__ nxt) {
    int e = blockIdx.x * blockDim.x + threadIdx.x;
    if (e < NE) {
        int h = dst[e] * 2 + (e & 1);
        nxt[e] = atomicExch(&head[h], e);
    }
}

// ---------------------------------------------------------------------------
// x (fp32) -> xb (bf16) + xf8 (fp8 e4m3, HW cvt)
// ---------------------------------------------------------------------------
__global__ void conv_x_kernel(const float* __restrict__ x, ushort* __restrict__ xb,
                              uint* __restrict__ xf8) {
    int i = blockIdx.x * 256 + threadIdx.x;
    if (i < NN * DF / 4) {
        float4 v = ((const float4*)x)[i];
        uint lo = (uint)f2bf(v.x) | ((uint)f2bf(v.y) << 16);
        uint hi = (uint)f2bf(v.z) | ((uint)f2bf(v.w) << 16);
        ((uint2*)xb)[i] = make_uint2(lo, hi);
        uint p = (uint)__builtin_amdgcn_cvt_pk_fp8_f32(v.x, v.y, 0, false);
        p = (uint)__builtin_amdgcn_cvt_pk_fp8_f32(v.z, v.w, (int)p, true);
        xf8[i] = p;
    }
}

// ---------------------------------------------------------------------------
// hb (bf16) -> hf8 (fp8 e4m3), 8 elements per thread
// ---------------------------------------------------------------------------
__global__ void conv_h_kernel(const ushort* __restrict__ hb, uint* __restrict__ hf8) {
    int i = blockIdx.x * 256 + threadIdx.x;
    if (i < NN * DF / 8) {
        uint4 v = ((const uint4*)hb)[i];
        uint a = (uint)__builtin_amdgcn_cvt_pk_fp8_f32(bf2f_lo(v.x), bf2f_hi(v.x), 0, false);
        a = (uint)__builtin_amdgcn_cvt_pk_fp8_f32(bf2f_lo(v.y), bf2f_hi(v.y), (int)a, true);
        uint b = (uint)__builtin_amdgcn_cvt_pk_fp8_f32(bf2f_lo(v.z), bf2f_hi(v.z), 0, false);
        b = (uint)__builtin_amdgcn_cvt_pk_fp8_f32(bf2f_lo(v.w), bf2f_hi(v.w), (int)b, true);
        ((uint2*)hf8)[i] = make_uint2(a, b);
    }
}

// ---------------------------------------------------------------------------
// W^T build: WT[n][k] (n<128, k<256) = bf16( k<128 ? Wl[k][n] : Wr[k-128][n] )
// ---------------------------------------------------------------------------
__global__ void conv_w_kernel(const float* __restrict__ W1l, const float* __restrict__ W1r,
                              const float* __restrict__ W2l, const float* __restrict__ W2r,
                              ushort* __restrict__ WT1, ushort* __restrict__ WT2) {
    int id = blockIdx.x * 256 + threadIdx.x;
    if (id < 128 * 256) {
        int n = id >> 8, k = id & 255;
        float a = (k < 128) ? W1l[k * 128 + n] : W1r[(k - 128) * 128 + n];
        float b = (k < 128) ? W2l[k * 128 + n] : W2r[(k - 128) * 128 + n];
        WT1[id] = f2bf(a);
        WT2[id] = f2bf(b);
    }
}

// ---------------------------------------------------------------------------
// Mean aggregation over fp8 rows via linked-list chase.
// 8 lanes per node (lane reads uint4 = 16 fp8), 32 nodes per 256-block,
// dual chains -> 16 independent chase streams per wave.
// fp32 accumulate (v_pk_add via floatx2), bf16 output.
// ---------------------------------------------------------------------------
static __device__ __forceinline__ void accf8(floatx2* ac, uint4 v) {
    ac[0] += __builtin_amdgcn_cvt_pk_f32_fp8((int)v.x, false);
    ac[1] += __builtin_amdgcn_cvt_pk_f32_fp8((int)v.x, true);
    ac[2] += __builtin_amdgcn_cvt_pk_f32_fp8((int)v.y, false);
    ac[3] += __builtin_amdgcn_cvt_pk_f32_fp8((int)v.y, true);
    ac[4] += __builtin_amdgcn_cvt_pk_f32_fp8((int)v.z, false);
    ac[5] += __builtin_amdgcn_cvt_pk_f32_fp8((int)v.z, true);
    ac[6] += __builtin_amdgcn_cvt_pk_f32_fp8((int)v.w, false);
    ac[7] += __builtin_amdgcn_cvt_pk_f32_fp8((int)v.w, true);
}

__global__ __launch_bounds__(256) void agg_f8(const uint* __restrict__ feat8,
                                              const int* __restrict__ src,
                                              const int* __restrict__ head,
                                              const int* __restrict__ nxt,
                                              ushort* __restrict__ aggb) {
    int g = threadIdx.x >> 3;       // node slot 0..31
    int l = threadIdx.x & 7;        // 16B chunk within 128B fp8 row
    int n = blockIdx.x * 32 + g;    // NN % 32 == 0
    const uint4* fb = (const uint4*)feat8;  // row stride = 8 uint4

    int c0 = head[n * 2];
    int c1 = head[n * 2 + 1];
    floatx2 ac[8];
    #pragma unroll
    for (int t = 0; t < 8; ++t) ac[t] = (floatx2){0.f, 0.f};
    int cnt = 0;

    while (c0 >= 0 && c1 >= 0) {
        int n0 = nxt[c0], n1 = nxt[c1];
        int s0 = src[c0], s1 = src[c1];
        uint4 v0 = fb[(size_t)s0 * 8 + l];
        uint4 v1 = fb[(size_t)s1 * 8 + l];
        accf8(ac, v0);
        accf8(ac, v1);
        cnt += 2;
        c0 = n0; c1 = n1;
    }
    while (c0 >= 0) {
        int n0 = nxt[c0];
        uint4 v = fb[(size_t)src[c0] * 8 + l];
        accf8(ac, v);
        cnt++;
        c0 = n0;
    }
    while (c1 >= 0) {
        int n1 = nxt[c1];
        uint4 v = fb[(size_t)src[c1] * 8 + l];
        accf8(ac, v);
        cnt++;
        c1 = n1;
    }

    float inv = 1.0f / fmaxf((float)cnt, 1.0f);
    uint o[8];
    #pragma unroll
    for (int t = 0; t < 8; ++t)
        o[t] = (uint)f2bf(ac[t].x * inv) | ((uint)f2bf(ac[t].y * inv) << 16);
    uint4* ob = (uint4*)aggb;       // row stride = 16 uint4 (256B bf16 row)
    ob[(size_t)n * 16 + l * 2]     = make_uint4(o[0], o[1], o[2], o[3]);
    ob[(size_t)n * 16 + l * 2 + 1] = make_uint4(o[4], o[5], o[6], o[7]);
}

// ---------------------------------------------------------------------------
// Fused GEMM: C[n,j] = act( [agg|self][n,:] @ WT[j,:] + bias[j] ), K=256.
// 512 threads = 8 waves, 128 rows/block. WT staged in LDS (XOR swizzle, 64KB).
// A-fragments straight from global.
// ---------------------------------------------------------------------------
template <int RELU, int BF16OUT>
__global__ __launch_bounds__(512, 4) void gemm_mfma(
        const ushort* __restrict__ aggb, const ushort* __restrict__ selfb,
        const ushort* __restrict__ WT, const float* __restrict__ bias,
        void* __restrict__ outv) {
    __shared__ ushort sWT[128 * 256];            // 64KB, swizzled chunks
    const int tid = threadIdx.x;
    const int blk = blockIdx.x;

    #pragma unroll
    for (int it = 0; it < 8; ++it) {
        int flat = it * 512 + tid;               // 0..4095
        int col = flat >> 5;
        int c = flat & 31;
        uint4 v = *(const uint4*)(WT + (size_t)col * 256 + c * 8);
        *(uint4*)&sWT[col * 256 + (c ^ (col & 7)) * 8] = v;
    }

    const int w = tid >> 6;
    const int lane = tid & 63;
    const int m = lane & 15;
    const int q = lane >> 4;

    int node_m = blk * 128 + w * 16 + m;
    int cn = node_m < NN ? node_m : NN - 1;
    const ushort* arow = aggb + (size_t)cn * 128;
    const ushort* xrow = selfb + (size_t)cn * 128;
    short8 a[8];
    #pragma unroll
    for (int kk = 0; kk < 4; ++kk) {
        a[kk]     = *(const short8*)(arow + kk * 32 + q * 8);
        a[4 + kk] = *(const short8*)(xrow + kk * 32 + q * 8);
    }

    __syncthreads();

    floatx4 acc[8];
    #pragma unroll
    for (int t = 0; t < 8; ++t) acc[t] = (floatx4){0.f, 0.f, 0.f, 0.f};

    const int m7 = m & 7;
    #pragma unroll
    for (int kk = 0; kk < 8; ++kk) {
        int cx = (kk * 4 + q) ^ m7;
        #pragma unroll
        for (int t = 0; t < 8; ++t) {
            short8 b = *(const short8*)&sWT[(t * 16 + m) * 256 + cx * 8];
            acc[t] = __builtin_amdgcn_mfma_f32_16x16x32_bf16(a[kk], b, acc[t], 0, 0, 0);
        }
    }

    const int node_base = blk * 128 + w * 16 + q * 4;
    #pragma unroll
    for (int t = 0; t < 8; ++t) {
        int col = t * 16 + m;
        float bj = bias[col];
        #pragma unroll
        for (int r = 0; r < 4; ++r) {
            int node = node_base + r;
            if (node < NN) {
                float v = acc[t][r] + bj;
                if (RELU) v = fmaxf(v, 0.0f);
                if (BF16OUT)
                    ((ushort*)outv)[(size_t)node * 128 + col] = f2bf(v);
                else
                    ((float*)outv)[(size_t)node * 128 + col] = v;
            }
        }
    }
}

// ---------------------------------------------------------------------------
extern "C" void kernel_launch(void* const* d_in, const int* in_sizes, int n_in,
                              void* d_out, int out_size, void* d_ws, size_t ws_size,
                              hipStream_t stream) {
    const float* x   = (const float*)d_in[0];
    const int*   ei  = (const int*)d_in[1];
    const float* W1l = (const float*)d_in[2];
    const float* b1  = (const float*)d_in[3];
    const float* W1r = (const float*)d_in[4];
    const float* W2l = (const float*)d_in[5];
    const float* b2  = (const float*)d_in[6];
    const float* W2r = (const float*)d_in[7];
    float*       out = (float*)d_out;

    const int* src = ei;
    const int* dst = ei + NE;

    // workspace layout (bytes), total 96.93 MB
    char* ws = (char*)d_ws;
    int*    head = (int*)(ws);                   // 800000
    int*    nxt  = (int*)(ws + 800000);          // 6400000
    ushort* WT1  = (ushort*)(ws + 7200000);      // 65536
    ushort* WT2  = (ushort*)(ws + 7265536);      // 65536
    ushort* xb   = (ushort*)(ws + 7331072);      // 25600000
    uint*   xf8  = (uint*)(ws + 32931072);       // 12800000 (reused as hf8)
    ushort* aggb = (ushort*)(ws + 45731072);     // 25600000
    ushort* hb   = (ushort*)(ws + 71331072);     // 25600000 (end 96.93MB)
    uint*   hf8  = xf8;                          // alias: xf8 dead after gemm1

    hipMemsetAsync(head, 0xFF, 800000, stream);  // heads = -1

    build_ll<<<(NE + 255) / 256, 256, 0, stream>>>(dst, head, nxt);
    conv_x_kernel<<<(NN * DF / 4 + 255) / 256, 256, 0, stream>>>(x, xb, xf8);
    conv_w_kernel<<<128, 256, 0, stream>>>(W1l, W1r, W2l, W2r, WT1, WT2);

    const int gemm_grid = (NN + 127) / 128;

    // ---- layer 1 ----
    agg_f8<<<NN / 32, 256, 0, stream>>>(xf8, src, head, nxt, aggb);
    gemm_mfma<1, 1><<<gemm_grid, 512, 0, stream>>>(aggb, xb, WT1, b1, hb);

    // ---- layer 2 ----
    conv_h_kernel<<<(NN * DF / 8 + 255) / 256, 256, 0, stream>>>(hb, hf8);
    agg_f8<<<NN / 32, 256, 0, stream>>>(hf8, src, head, nxt, aggb);
    gemm_mfma<0, 0><<<gemm_grid, 512, 0, stream>>>(aggb, hb, WT2, b2, out);
}